// Round 1
// baseline (598.951 us; speedup 1.0000x reference)
//
#include <hip/hip_runtime.h>
#include <hip/hip_bf16.h>
#include <math.h>

#define M 4096
#define N 8192
#define K 128
#define NSAMP 8192
#define VOCABF 1000000.0f

typedef __bf16 bf16x8 __attribute__((ext_vector_type(8)));
typedef float f32x16 __attribute__((ext_vector_type(16)));
typedef unsigned short u16x8 __attribute__((ext_vector_type(8)));

// RNE float->bf16 (inputs are finite normals; NaN path not needed)
__device__ inline unsigned short f2bf(float f) {
    unsigned int u = __float_as_uint(f);
    unsigned int r = (u + 0x7FFFu + ((u >> 16) & 1u)) >> 16;
    return (unsigned short)r;
}

// ---- prep: predictions f32 -> bf16 -------------------------------------
__global__ __launch_bounds__(256) void prep_p(const float* __restrict__ pred,
                                              unsigned short* __restrict__ Pb) {
    int t = blockIdx.x * 256 + threadIdx.x;     // 65536 threads, 8 elems each
    int base = t * 8;
    float4 f0 = *(const float4*)(pred + base);
    float4 f1 = *(const float4*)(pred + base + 4);
    u16x8 v;
    v[0] = f2bf(f0.x); v[1] = f2bf(f0.y); v[2] = f2bf(f0.z); v[3] = f2bf(f0.w);
    v[4] = f2bf(f1.x); v[5] = f2bf(f1.y); v[6] = f2bf(f1.z); v[7] = f2bf(f1.w);
    *(u16x8*)(Pb + base) = v;
}

// ---- prep: gather sampled W rows -> bf16, compute bias corrections -----
__global__ __launch_bounds__(256) void prep_w(const int* __restrict__ sampled,
                                              const float* __restrict__ W,
                                              const float* __restrict__ bias,
                                              unsigned short* __restrict__ Wsb,
                                              float* __restrict__ bcorr) {
    int t = blockIdx.x * 256 + threadIdx.x;     // 131072 threads: 16 per row
    int s = t >> 4, c = t & 15;
    int id = sampled[s];
    const float* src = W + (size_t)id * K + c * 8;
    float4 f0 = *(const float4*)src;
    float4 f1 = *(const float4*)(src + 4);
    u16x8 v;
    v[0] = f2bf(f0.x); v[1] = f2bf(f0.y); v[2] = f2bf(f0.z); v[3] = f2bf(f0.w);
    v[4] = f2bf(f1.x); v[5] = f2bf(f1.y); v[6] = f2bf(f1.z); v[7] = f2bf(f1.w);
    *(u16x8*)(Wsb + s * K + c * 8) = v;
    if (c == 0) {
        float kk = (float)id;
        // log(k+2)-log(k+1) computed as log1p(1/(k+1)) to avoid catastrophic
        // cancellation at k ~ 1e6 (ref's f32 version has ~1ulp noise there;
        // systematic part cancels between LSE and true-logit terms)
        float q = log1pf(1.0f / (kk + 1.0f)) / logf(VOCABF + 1.0f);
        bcorr[s] = bias[id] - logf((float)NSAMP * q);
    }
}

// ---- main: bf16 MFMA GEMM + exp + per-row sum --------------------------
// grid (32,32): blockIdx.x -> 128-row strip, blockIdx.y -> 256-col strip
// 4 waves: each wave owns 32 rows, iterates 8 n-tiles of 32 cols, K=128.
__global__ __launch_bounds__(256, 4) void main_gemm(
        const unsigned short* __restrict__ Pb,
        const unsigned short* __restrict__ Wsb,
        const float* __restrict__ bcorr,
        float* __restrict__ row_sum) {
    const int tid  = threadIdx.x;
    const int lane = tid & 63;
    const int wid  = tid >> 6;         // 0..3: m-wave
    const int l31  = lane & 31;
    const int half = lane >> 5;        // 0/1
    const int mrow = blockIdx.x * 128 + wid * 32 + l31;
    const int nb   = blockIdx.y * 256;

    // A fragments for all of K=128, held in registers (32 VGPRs)
    // layout: A[m = lane&31][k = (lane>>5)*8 + j], k-step stride 16
    bf16x8 a[8];
    const unsigned short* ap = Pb + (size_t)mrow * K + half * 8;
#pragma unroll
    for (int ks = 0; ks < 8; ++ks)
        a[ks] = *(const bf16x8*)(ap + ks * 16);

    float rs[16];
#pragma unroll
    for (int r = 0; r < 16; ++r) rs[r] = 0.0f;

#pragma unroll
    for (int t = 0; t < 8; ++t) {
        const int col = nb + t * 32 + l31;
        const float bc = bcorr[col];          // same col for all 16 acc regs
        f32x16 acc;
#pragma unroll
        for (int r = 0; r < 16; ++r) acc[r] = bc;   // bias folded into C-init
        const unsigned short* bp = Wsb + (size_t)col * K + half * 8;
#pragma unroll
        for (int ks = 0; ks < 8; ++ks) {
            bf16x8 bf = *(const bf16x8*)(bp + ks * 16);
            acc = __builtin_amdgcn_mfma_f32_32x32x16_bf16(a[ks], bf, acc, 0, 0, 0);
        }
        // logits bounded in ~[-9, +11]: exp-sum safe in f32 without max-sub
#pragma unroll
        for (int r = 0; r < 16; ++r) rs[r] += __expf(acc[r]);
    }

    // reduce across the 32 cols (lanes of each half-wave share rows)
#pragma unroll
    for (int m = 1; m <= 16; m <<= 1) {
#pragma unroll
        for (int r = 0; r < 16; ++r) rs[r] += __shfl_xor(rs[r], m, 64);
    }
    if (l31 == 0) {
        const int rb = blockIdx.x * 128 + wid * 32 + 4 * half;
#pragma unroll
        for (int r = 0; r < 16; ++r) {
            int row = rb + (r & 3) + 8 * (r >> 2);  // verified C/D row map
            atomicAdd(&row_sum[row], rs[r]);
        }
    }
}

// ---- finalize: true logits (f32), per-row loss, mean -------------------
__global__ __launch_bounds__(256) void finalize(const float* __restrict__ pred,
                                                const int* __restrict__ labels,
                                                const float* __restrict__ W,
                                                const float* __restrict__ bias,
                                                const float* __restrict__ row_sum,
                                                float* __restrict__ out) {
    __shared__ float part[16];
    int t = blockIdx.x * 256 + threadIdx.x;   // 16 threads per row
    int row = t >> 4, c = t & 15;
    int id = labels[row];
    const float* wp = W + (size_t)id * K + c * 8;
    const float* pp = pred + (size_t)row * K + c * 8;
    float4 w0 = *(const float4*)wp, w1 = *(const float4*)(wp + 4);
    float4 p0 = *(const float4*)pp, p1 = *(const float4*)(pp + 4);
    float d = w0.x * p0.x + w0.y * p0.y + w0.z * p0.z + w0.w * p0.w
            + w1.x * p1.x + w1.y * p1.y + w1.z * p1.z + w1.w * p1.w;
#pragma unroll
    for (int m = 1; m <= 8; m <<= 1) d += __shfl_xor(d, m, 64);
    if (c == 0) {
        float kk = (float)id;
        float q = log1pf(1.0f / (kk + 1.0f)) / logf(VOCABF + 1.0f);
        float tl = d + bias[id] - logf((float)NSAMP * q);
        float loss = logf(row_sum[row] + __expf(tl)) - tl;
        part[threadIdx.x >> 4] = loss;
    }
    __syncthreads();
    if (threadIdx.x == 0) {
        float s = 0.0f;
#pragma unroll
        for (int i = 0; i < 16; ++i) s += part[i];
        atomicAdd(out, s * (1.0f / (float)M));
    }
}

extern "C" void kernel_launch(void* const* d_in, const int* in_sizes, int n_in,
                              void* d_out, int out_size, void* d_ws, size_t ws_size,
                              hipStream_t stream) {
    const float* pred    = (const float*)d_in[0];
    const int*   labels  = (const int*)d_in[1];
    const int*   sampled = (const int*)d_in[2];
    const float* W       = (const float*)d_in[3];
    const float* b       = (const float*)d_in[4];
    float* out = (float*)d_out;

    char* ws = (char*)d_ws;
    unsigned short* Wsb   = (unsigned short*)ws;                       // 2 MB
    unsigned short* Pb    = (unsigned short*)(ws + (1 << 21));         // 1 MB
    float*          bcorr = (float*)(ws + (1 << 21) + (1 << 20));      // 32 KB
    float*          rsum  = (float*)(ws + (1 << 21) + (1 << 20) + NSAMP * 4);

    hipMemsetAsync(rsum, 0, M * sizeof(float), stream);
    hipMemsetAsync(out, 0, sizeof(float), stream);
    prep_p<<<256, 256, 0, stream>>>(pred, Pb);
    prep_w<<<512, 256, 0, stream>>>(sampled, W, b, Wsb, bcorr);
    main_gemm<<<dim3(32, 32), 256, 0, stream>>>(Pb, Wsb, bcorr, rsum);
    finalize<<<256, 256, 0, stream>>>(pred, labels, W, b, rsum, out);
}

// Round 2
// 593.473 us; speedup vs baseline: 1.0092x; 1.0092x over previous
//
#include <hip/hip_runtime.h>
#include <hip/hip_bf16.h>
#include <math.h>

#define M 4096
#define N 8192
#define K 128
#define NSAMP 8192
#define VOCABF 1000000.0f

typedef __bf16 bf16x8 __attribute__((ext_vector_type(8)));
typedef float f32x16 __attribute__((ext_vector_type(16)));
typedef unsigned short u16x8 __attribute__((ext_vector_type(8)));

// RNE float->bf16 (inputs are finite normals; NaN path not needed)
__device__ inline unsigned short f2bf(float f) {
    unsigned int u = __float_as_uint(f);
    unsigned int r = (u + 0x7FFFu + ((u >> 16) & 1u)) >> 16;
    return (unsigned short)r;
}

// ---- fused prep: P->bf16, gather W rows->bf16, bias corr, zero rsum/out ----
// blocks [0,256): predictions convert (65536 threads, 8 elems each) + zero-init
// blocks [256,768): sampled-row gather (131072 threads, 16 per row)
__global__ __launch_bounds__(256) void prep(const float* __restrict__ pred,
                                            const int* __restrict__ sampled,
                                            const float* __restrict__ W,
                                            const float* __restrict__ bias,
                                            unsigned short* __restrict__ Pb,
                                            unsigned short* __restrict__ Wsb,
                                            float* __restrict__ bcorr,
                                            float* __restrict__ rsum,
                                            float* __restrict__ out) {
    const int bx = blockIdx.x;
    if (bx < 256) {
        int t = bx * 256 + threadIdx.x;
        if (t < M) rsum[t] = 0.0f;          // fold memsets into this kernel
        if (t == 0) out[0] = 0.0f;
        int base = t * 8;
        float4 f0 = *(const float4*)(pred + base);
        float4 f1 = *(const float4*)(pred + base + 4);
        u16x8 v;
        v[0] = f2bf(f0.x); v[1] = f2bf(f0.y); v[2] = f2bf(f0.z); v[3] = f2bf(f0.w);
        v[4] = f2bf(f1.x); v[5] = f2bf(f1.y); v[6] = f2bf(f1.z); v[7] = f2bf(f1.w);
        *(u16x8*)(Pb + base) = v;
    } else {
        int t = (bx - 256) * 256 + threadIdx.x;
        int s = t >> 4, c = t & 15;
        int id = sampled[s];
        const float* src = W + (size_t)id * K + c * 8;
        float4 f0 = *(const float4*)src;
        float4 f1 = *(const float4*)(src + 4);
        u16x8 v;
        v[0] = f2bf(f0.x); v[1] = f2bf(f0.y); v[2] = f2bf(f0.z); v[3] = f2bf(f0.w);
        v[4] = f2bf(f1.x); v[5] = f2bf(f1.y); v[6] = f2bf(f1.z); v[7] = f2bf(f1.w);
        *(u16x8*)(Wsb + s * K + c * 8) = v;
        if (c == 0) {
            float kk = (float)id;
            // log(k+2)-log(k+1) as log1p(1/(k+1)): avoids f32 cancellation at k~1e6
            float q = log1pf(1.0f / (kk + 1.0f)) / logf(VOCABF + 1.0f);
            bcorr[s] = bias[id] - logf((float)NSAMP * q);
        }
    }
}

// ---- main: bf16 MFMA GEMM + exp + per-row sum --------------------------
// grid (32,32): blockIdx.x -> 128-row strip, blockIdx.y -> 256-col strip
// 4 waves: each wave owns 32 rows, iterates 8 n-tiles of 32 cols, K=128.
__global__ __launch_bounds__(256, 4) void main_gemm(
        const unsigned short* __restrict__ Pb,
        const unsigned short* __restrict__ Wsb,
        const float* __restrict__ bcorr,
        float* __restrict__ row_sum) {
    const int tid  = threadIdx.x;
    const int lane = tid & 63;
    const int wid  = tid >> 6;         // 0..3: m-wave
    const int l31  = lane & 31;
    const int half = lane >> 5;        // 0/1
    const int mrow = blockIdx.x * 128 + wid * 32 + l31;
    const int nb   = blockIdx.y * 256;

    // A fragments for all of K=128, held in registers (32 VGPRs)
    // layout: A[m = lane&31][k = (lane>>5)*8 + j], k-step stride 16
    bf16x8 a[8];
    const unsigned short* ap = Pb + (size_t)mrow * K + half * 8;
#pragma unroll
    for (int ks = 0; ks < 8; ++ks)
        a[ks] = *(const bf16x8*)(ap + ks * 16);

    float rs[16];
#pragma unroll
    for (int r = 0; r < 16; ++r) rs[r] = 0.0f;

#pragma unroll
    for (int t = 0; t < 8; ++t) {
        const int col = nb + t * 32 + l31;
        const float bc = bcorr[col];          // same col for all 16 acc regs
        f32x16 acc;
#pragma unroll
        for (int r = 0; r < 16; ++r) acc[r] = bc;   // bias folded into C-init
        const unsigned short* bp = Wsb + (size_t)col * K + half * 8;
#pragma unroll
        for (int ks = 0; ks < 8; ++ks) {
            bf16x8 bf = *(const bf16x8*)(bp + ks * 16);
            acc = __builtin_amdgcn_mfma_f32_32x32x16_bf16(a[ks], bf, acc, 0, 0, 0);
        }
        // logits bounded in ~[-9, +11]: exp-sum safe in f32 without max-sub
#pragma unroll
        for (int r = 0; r < 16; ++r) rs[r] += __expf(acc[r]);
    }

    // reduce across the 32 cols (lanes of each half-wave share rows)
#pragma unroll
    for (int m = 1; m <= 16; m <<= 1) {
#pragma unroll
        for (int r = 0; r < 16; ++r) rs[r] += __shfl_xor(rs[r], m, 64);
    }
    if (l31 == 0) {
        const int rb = blockIdx.x * 128 + wid * 32 + 4 * half;
#pragma unroll
        for (int r = 0; r < 16; ++r) {
            int row = rb + (r & 3) + 8 * (r >> 2);  // verified C/D row map
            atomicAdd(&row_sum[row], rs[r]);
        }
    }
}

// ---- finalize: true logits (f32), per-row loss, mean -------------------
__global__ __launch_bounds__(256) void finalize(const float* __restrict__ pred,
                                                const int* __restrict__ labels,
                                                const float* __restrict__ W,
                                                const float* __restrict__ bias,
                                                const float* __restrict__ row_sum,
                                                float* __restrict__ out) {
    __shared__ float part[16];
    int t = blockIdx.x * 256 + threadIdx.x;   // 16 threads per row
    int row = t >> 4, c = t & 15;
    int id = labels[row];
    const float* wp = W + (size_t)id * K + c * 8;
    const float* pp = pred + (size_t)row * K + c * 8;
    float4 w0 = *(const float4*)wp, w1 = *(const float4*)(wp + 4);
    float4 p0 = *(const float4*)pp, p1 = *(const float4*)(pp + 4);
    float d = w0.x * p0.x + w0.y * p0.y + w0.z * p0.z + w0.w * p0.w
            + w1.x * p1.x + w1.y * p1.y + w1.z * p1.z + w1.w * p1.w;
#pragma unroll
    for (int m = 1; m <= 8; m <<= 1) d += __shfl_xor(d, m, 64);
    if (c == 0) {
        float kk = (float)id;
        float q = log1pf(1.0f / (kk + 1.0f)) / logf(VOCABF + 1.0f);
        float tl = d + bias[id] - logf((float)NSAMP * q);
        float loss = logf(row_sum[row] + __expf(tl)) - tl;
        part[threadIdx.x >> 4] = loss;
    }
    __syncthreads();
    if (threadIdx.x == 0) {
        float s = 0.0f;
#pragma unroll
        for (int i = 0; i < 16; ++i) s += part[i];
        atomicAdd(out, s * (1.0f / (float)M));
    }
}

extern "C" void kernel_launch(void* const* d_in, const int* in_sizes, int n_in,
                              void* d_out, int out_size, void* d_ws, size_t ws_size,
                              hipStream_t stream) {
    const float* pred    = (const float*)d_in[0];
    const int*   labels  = (const int*)d_in[1];
    const int*   sampled = (const int*)d_in[2];
    const float* W       = (const float*)d_in[3];
    const float* b       = (const float*)d_in[4];
    float* out = (float*)d_out;

    char* ws = (char*)d_ws;
    unsigned short* Wsb   = (unsigned short*)ws;                       // 2 MB
    unsigned short* Pb    = (unsigned short*)(ws + (1 << 21));         // 1 MB
    float*          bcorr = (float*)(ws + (1 << 21) + (1 << 20));      // 32 KB
    float*          rsum  = (float*)(ws + (1 << 21) + (1 << 20) + NSAMP * 4);

    prep<<<768, 256, 0, stream>>>(pred, sampled, W, b, Pb, Wsb, bcorr, rsum, out);
    main_gemm<<<dim3(32, 32), 256, 0, stream>>>(Pb, Wsb, bcorr, rsum);
    finalize<<<256, 256, 0, stream>>>(pred, labels, W, b, rsum, out);
}